// Round 2
// baseline (338.804 us; speedup 1.0000x reference)
//
#include <hip/hip_runtime.h>
#include <math.h>

// Problem constants: B=64, MAX_H=64, MAX_W=32, D=512, S=8, HID=64
#define NB    64
#define MAXH  64
#define MAXW  32
#define DCH   512
#define SS    8
#define HID   64

#define QTOTAL ((size_t)NB * MAXH * MAXW * DCH)   // 67,108,864 floats

typedef float f4 __attribute__((ext_vector_type(4)));

__device__ __forceinline__ float gelu_exact(float x) {
    // jax.nn.gelu(approximate=False): x * 0.5 * (1 + erf(x/sqrt(2)))
    return 0.5f * x * (1.0f + erff(x * 0.70710678118654752440f));
}

__global__ __launch_bounds__(256) void hgqg_kernel(
    const float* __restrict__ canonical,  // (8,8,512)
    const float* __restrict__ w1,         // (2,64)
    const float* __restrict__ b1,         // (64,)
    const float* __restrict__ w2,         // (64,512)
    const float* __restrict__ b2,         // (512,)
    const int*   __restrict__ hlist,      // (64,)
    const int*   __restrict__ wlist,      // (64,)
    float* __restrict__ out)              // queries flat, then mask flat
{
    const int blk = blockIdx.x;       // b*64 + i
    const int b   = blk >> 6;
    const int i   = blk & 63;
    const int t   = threadIdx.x;

    int H = hlist[b]; H = min(max(H, 1), MAXH);
    int W = wlist[b]; W = min(max(W, 1), MAXW);

    f4* q4 = (f4*)(out + (size_t)blk * (MAXW * DCH));

    // mask row: bool -> 0.0/1.0 floats
    if (t < MAXW) {
        out[QTOTAL + (size_t)blk * MAXW + t] = (i < H && t < W) ? 1.0f : 0.0f;
    }

    if (i >= H) {
        // whole row zero: 32*512 floats = 4096 f4; streaming stores
        const f4 z = {0.f, 0.f, 0.f, 0.f};
        #pragma unroll
        for (int r = 0; r < 16; ++r)
            __builtin_nontemporal_store(z, q4 + t + r * 256);
        return;
    }

    // ---- per-row uniforms ----
    const float u    = (H > 1) ? (float)i / (float)(H - 1) : 0.0f;
    const float sy   = fminf(u * 7.0f, 7.0f);           // u in [0,1]
    const int   y0   = (int)sy;
    const int   y1   = min(y0 + 1, SS - 1);
    const float wy   = sy - (float)y0;
    const float winv = (W > 1) ? 1.0f / (float)(W - 1) : 0.0f;

    // ---- stage A: y-lerped canonical rows -> LDS (16 KB) ----
    // ri[x*128 + c] = (1-wy)*can[y0][x][4c..] + wy*can[y1][x][4c..]
    __shared__ f4 ri[SS * 128];
    {
        const f4* can4 = (const f4*)canonical;
        #pragma unroll
        for (int r = 0; r < 4; ++r) {
            const int idx = t + r * 256;       // 0..1023
            const int x   = idx >> 7;
            const int c   = idx & 127;
            const f4 a = can4[(y0 * SS + x) * 128 + c];
            const f4 d = can4[(y1 * SS + x) * 128 + c];
            ri[idx] = a + wy * (d - a);
        }
    }

    // ---- stage B: h[j][k] = gelu(u*w1[0][k] + v_j*w1[1][k] + b1[k]) ----
    __shared__ __align__(16) float hsh[MAXW][HID];   // 8 KB
    {
        const int j  = t >> 3;             // 0..31
        const int k0 = (t & 7) * 8;        // 0..56
        const float v = (float)j * winv;
        #pragma unroll
        for (int kk = 0; kk < 8; ++kk) {
            const int k = k0 + kk;
            hsh[j][k] = gelu_exact(u * w1[k] + v * w1[HID + k] + b1[k]);
        }
    }
    __syncthreads();

    // ---- main: thread owns 4 channels (cid) for 16 interleaved j's ----
    const int cid = t & 127;          // channel/4 index 0..127
    const int jg  = t >> 7;           // 0 or 1; j = jg + 2s
    const f4  bb2 = ((const f4*)b2)[cid];

    f4 acc[16];

    // init: bilinear (x-lerp of LDS y-lerped rows) + b2 — branchless, all slots
    #pragma unroll
    for (int s = 0; s < 16; ++s) {
        const int   j  = jg + 2 * s;
        const float v  = (float)j * winv;
        const float sx = fminf(v * 7.0f, 7.0f);
        const int   x0 = (int)sx;
        const int   x1 = min(x0 + 1, SS - 1);
        const float wx = sx - (float)x0;
        const f4 f0 = ri[x0 * 128 + cid];
        const f4 f1 = ri[x1 * 128 + cid];
        acc[s] = f0 + wx * (f1 - f0) + bb2;
    }

    // GEMV: acc[j] += sum_k h[j][k] * w2[k][4c..], k-blocked by 4 with
    // explicit register double-buffering of the w2 loads.
    const f4* wp = (const f4*)w2 + cid;
    f4 wa = wp[0 * 128], wb = wp[1 * 128], wc = wp[2 * 128], wd = wp[3 * 128];
    #pragma unroll 1
    for (int kb = 0; kb < HID; kb += 4) {
        const int kn = (kb + 4 < HID) ? (kb + 4) : kb;   // last iter: harmless reload
        const f4 na = wp[(kn + 0) * 128];
        const f4 nb = wp[(kn + 1) * 128];
        const f4 nc = wp[(kn + 2) * 128];
        const f4 nd = wp[(kn + 3) * 128];
        #pragma unroll
        for (int s = 0; s < 16; ++s) {
            const int j = jg + 2 * s;
            const f4 h4 = *(const f4*)&hsh[j][kb];   // wave-uniform -> broadcast
            acc[s] += h4.x * wa + h4.y * wb + h4.z * wc + h4.w * wd;
        }
        wa = na; wb = nb; wc = nc; wd = nd;
    }

    // store: zero masked-out j's via cndmask, streaming stores
    const f4 z = {0.f, 0.f, 0.f, 0.f};
    #pragma unroll
    for (int s = 0; s < 16; ++s) {
        const int j = jg + 2 * s;
        const f4 o = (j < W) ? acc[s] : z;
        __builtin_nontemporal_store(o, q4 + j * 128 + cid);
    }
}

extern "C" void kernel_launch(void* const* d_in, const int* in_sizes, int n_in,
                              void* d_out, int out_size, void* d_ws, size_t ws_size,
                              hipStream_t stream) {
    const float* canonical = (const float*)d_in[0];
    const float* w1        = (const float*)d_in[1];
    const float* b1        = (const float*)d_in[2];
    const float* w2        = (const float*)d_in[3];
    const float* b2        = (const float*)d_in[4];
    const int*   hlist     = (const int*)d_in[6];
    const int*   wlist     = (const int*)d_in[7];
    float* out = (float*)d_out;

    hgqg_kernel<<<NB * MAXH, 256, 0, stream>>>(
        canonical, w1, b1, w2, b2, hlist, wlist, out);
}